// Round 1
// baseline (352.345 us; speedup 1.0000x reference)
//
#include <hip/hip_runtime.h>
#include <cmath>

typedef _Float16 half8 __attribute__((ext_vector_type(8)));
typedef _Float16 half4 __attribute__((ext_vector_type(4)));
typedef float floatx4 __attribute__((ext_vector_type(4)));

#define LDSS 40  // LDS row stride in halves (80 B = 20 dwords -> <=2-way conflicts, free)

// ---------------- prep: cast X fp32 -> fp16 ----------------
__global__ void cast_x_kernel(const float* __restrict__ x, _Float16* __restrict__ xh, int n4) {
  int i = blockIdx.x * blockDim.x + threadIdx.x;
  if (i < n4) {
    float4 v = ((const float4*)x)[i];
    half4 h;
    h[0] = (_Float16)v.x; h[1] = (_Float16)v.y; h[2] = (_Float16)v.z; h[3] = (_Float16)v.w;
    ((half4*)xh)[i] = h;
  }
}

// ---------------- prep: W[k][n] fp32 -> Wt[n][k] fp16 (combined Q|K|V) ----------------
__global__ void wt_kernel(const float* __restrict__ Wq, const float* __restrict__ Wk,
                          const float* __restrict__ Wv, _Float16* __restrict__ Wt) {
  __shared__ float tile[32][33];
  int n0 = blockIdx.x * 32, k0 = blockIdx.y * 32, w = blockIdx.z;
  const float* src = (w == 0) ? Wq : (w == 1) ? Wk : Wv;
  int c = threadIdx.x & 31, r8 = threadIdx.x >> 5;
  for (int p = 0; p < 4; ++p) {
    int r = p * 8 + r8;
    tile[r][c] = src[(size_t)(k0 + r) * 1024 + n0 + c];
  }
  __syncthreads();
  for (int p = 0; p < 4; ++p) {
    int rr = p * 8 + r8;  // n within tile
    Wt[(size_t)(w * 1024 + n0 + rr) * 1024 + k0 + c] = (_Float16)tile[c][rr];
  }
}

// ---------------- V[t][d] -> Vt[d][t] fp16 ----------------
__global__ void vt_kernel(const _Float16* __restrict__ V, _Float16* __restrict__ Vt) {
  __shared__ _Float16 tile[32][33];
  int t0 = blockIdx.x * 32, d0 = blockIdx.y * 32, b = blockIdx.z;
  const _Float16* Vb = V + (size_t)b * 2048 * 1024;
  _Float16* Vtb = Vt + (size_t)b * 1024 * 2048;
  int c = threadIdx.x & 31, r8 = threadIdx.x >> 5;
  for (int p = 0; p < 4; ++p) {
    int r = p * 8 + r8;
    tile[r][c] = Vb[(size_t)(t0 + r) * 1024 + d0 + c];
  }
  __syncthreads();
  for (int p = 0; p < 4; ++p) {
    int rr = p * 8 + r8;  // d within tile
    Vtb[(size_t)(d0 + rr) * 2048 + t0 + c] = tile[c][rr];
  }
}

// ---------------- shared GEMM core: C128x128 += A[m][k] * B[n][k]^T ----------------
// A: row-major [M][lda] (k contiguous), B: row-major [N][ldb] (k contiguous).
// 256 threads = 4 waves in 2x2; each wave does 64x64 via 4x4 of 16x16x32 MFMA.
__device__ __forceinline__ void gemm_core(const _Float16* __restrict__ A, int lda, int m0,
                                          const _Float16* __restrict__ B, int ldb, int n0,
                                          int kIters, _Float16* sA, _Float16* sB,
                                          floatx4 acc[4][4]) {
  int tid = threadIdx.x;
  int lane = tid & 63, wave = tid >> 6;
  int wm = (wave >> 1) << 6, wn = (wave & 1) << 6;
  int quad = lane >> 4, r = lane & 15;
  int kc = quad << 3;
  for (int kt = 0; kt < kIters; ++kt) {
    int kb = kt << 5;
    __syncthreads();
    for (int c = tid; c < 512; c += 256) {
      int row = c >> 2, kk = (c & 3) << 3;
      *(half8*)(sA + row * LDSS + kk) = *(const half8*)(A + (size_t)(m0 + row) * lda + kb + kk);
    }
    for (int c = tid; c < 512; c += 256) {
      int row = c >> 2, kk = (c & 3) << 3;
      *(half8*)(sB + row * LDSS + kk) = *(const half8*)(B + (size_t)(n0 + row) * ldb + kb + kk);
    }
    __syncthreads();
    half8 af[4], bf[4];
    for (int i = 0; i < 4; ++i) af[i] = *(const half8*)(sA + (wm + i * 16 + r) * LDSS + kc);
    for (int j = 0; j < 4; ++j) bf[j] = *(const half8*)(sB + (wn + j * 16 + r) * LDSS + kc);
    for (int i = 0; i < 4; ++i)
      for (int j = 0; j < 4; ++j)
        acc[i][j] = __builtin_amdgcn_mfma_f32_16x16x32_f16(af[i], bf[j], acc[i][j], 0, 0, 0);
  }
}

// ---------------- QKV projection: [8192x1024] x [3072x1024]^T ----------------
__global__ void qkv_kernel(const _Float16* __restrict__ X, const _Float16* __restrict__ Wt,
                           _Float16* __restrict__ Q, _Float16* __restrict__ K,
                           _Float16* __restrict__ Vv) {
  __shared__ __align__(16) _Float16 sA[128 * LDSS];
  __shared__ __align__(16) _Float16 sB[128 * LDSS];
  floatx4 acc[4][4];
  for (int i = 0; i < 4; ++i)
    for (int j = 0; j < 4; ++j) acc[i][j] = (floatx4){0.f, 0.f, 0.f, 0.f};
  int m0 = blockIdx.y * 128, n0 = blockIdx.x * 128;
  gemm_core(X, 1024, m0, Wt, 1024, n0, 32, sA, sB, acc);
  int lane = threadIdx.x & 63, wave = threadIdx.x >> 6;
  int wm = (wave >> 1) << 6, wn = (wave & 1) << 6;
  int quad = lane >> 4, cl = lane & 15;
  int which = n0 >> 10;  // whole block maps to one of Q/K/V (128 | 1024)
  _Float16* dst = (which == 0) ? Q : (which == 1) ? K : Vv;
  int colbase = (n0 & 1023) + wn;
  for (int i = 0; i < 4; ++i)
    for (int j = 0; j < 4; ++j)
      for (int rr = 0; rr < 4; ++rr) {
        int row = m0 + wm + i * 16 + quad * 4 + rr;
        int col = colbase + j * 16 + cl;
        dst[(size_t)row * 1024 + col] = (_Float16)acc[i][j][rr];
      }
}

// ---------------- scores: S[t][s] = Q.K^T / 32, lower-triangular tiles only ----------------
__global__ void qk_kernel(const _Float16* __restrict__ Q, const _Float16* __restrict__ K,
                          _Float16* __restrict__ S) {
  __shared__ __align__(16) _Float16 sA[128 * LDSS];
  __shared__ __align__(16) _Float16 sB[128 * LDSS];
  int p = blockIdx.x, b = blockIdx.y;
  int ti = 0;
  while ((ti + 1) * (ti + 2) / 2 <= p) ++ti;
  int tj = p - ti * (ti + 1) / 2;
  const _Float16* Qb = Q + (size_t)b * 2048 * 1024;
  const _Float16* Kb = K + (size_t)b * 2048 * 1024;
  _Float16* Sb = S + (size_t)b * 2048 * 2048;
  floatx4 acc[4][4];
  for (int i = 0; i < 4; ++i)
    for (int j = 0; j < 4; ++j) acc[i][j] = (floatx4){0.f, 0.f, 0.f, 0.f};
  gemm_core(Qb, 1024, ti * 128, Kb, 1024, tj * 128, 32, sA, sB, acc);
  int lane = threadIdx.x & 63, wave = threadIdx.x >> 6;
  int wm = (wave >> 1) << 6, wn = (wave & 1) << 6;
  int quad = lane >> 4, cl = lane & 15;
  for (int i = 0; i < 4; ++i)
    for (int j = 0; j < 4; ++j)
      for (int rr = 0; rr < 4; ++rr) {
        int row = ti * 128 + wm + i * 16 + quad * 4 + rr;
        int col = tj * 128 + wn + j * 16 + cl;
        float val = acc[i][j][rr] * 0.03125f;  // 1/sqrt(1024)
        if (col > row) val = -INFINITY;        // causal mask (diagonal tiles)
        Sb[(size_t)row * 2048 + col] = (_Float16)val;
      }
}

// ---------------- row softmax in place (fp16 S -> fp16 P) ----------------
__global__ void softmax_kernel(_Float16* __restrict__ S) {
  __shared__ float srow[2048];
  __shared__ float redm[4];
  __shared__ float reds[4];
  int idx = blockIdx.x;
  int b = idx >> 11, t = idx & 2047;
  _Float16* row = S + ((size_t)b * 2048 + t) * 2048;
  int rowlen = ((t >> 7) + 1) << 7;  // tile-aligned valid length
  int nch = rowlen >> 3;
  int tid = threadIdx.x;
  int lane = tid & 63, wv = tid >> 6;
  float mx = -INFINITY;
  for (int c = tid; c < nch; c += 256) {
    half8 h = *(const half8*)(row + c * 8);
    for (int e = 0; e < 8; ++e) {
      float f = (float)h[e];
      srow[c * 8 + e] = f;
      mx = fmaxf(mx, f);
    }
  }
  for (int o = 32; o; o >>= 1) mx = fmaxf(mx, __shfl_down(mx, o, 64));
  if (lane == 0) redm[wv] = mx;
  __syncthreads();
  mx = fmaxf(fmaxf(redm[0], redm[1]), fmaxf(redm[2], redm[3]));
  float sum = 0.f;
  for (int c = tid; c < nch; c += 256) {
    for (int e = 0; e < 8; ++e) {
      float ev = __expf(srow[c * 8 + e] - mx);  // exp(-inf)=0 handles mask
      srow[c * 8 + e] = ev;
      sum += ev;
    }
  }
  for (int o = 32; o; o >>= 1) sum += __shfl_down(sum, o, 64);
  if (lane == 0) reds[wv] = sum;
  __syncthreads();
  sum = reds[0] + reds[1] + reds[2] + reds[3];
  float inv = 1.0f / sum;
  for (int c = tid; c < nch; c += 256) {
    half8 h;
    for (int e = 0; e < 8; ++e) h[e] = (_Float16)(srow[c * 8 + e] * inv);
    *(half8*)(row + c * 8) = h;
  }
}

// ---------------- O = P.V : [2048x(kmax)] x [1024x2048]^T, fp32 out ----------------
__global__ void pv_kernel(const _Float16* __restrict__ P, const _Float16* __restrict__ Vt,
                          float* __restrict__ out) {
  __shared__ __align__(16) _Float16 sA[128 * LDSS];
  __shared__ __align__(16) _Float16 sB[128 * LDSS];
  int n0 = blockIdx.x * 128, ti = blockIdx.y, b = blockIdx.z;
  const _Float16* Pb = P + (size_t)b * 2048 * 2048;
  const _Float16* Vb = Vt + (size_t)b * 1024 * 2048;
  floatx4 acc[4][4];
  for (int i = 0; i < 4; ++i)
    for (int j = 0; j < 4; ++j) acc[i][j] = (floatx4){0.f, 0.f, 0.f, 0.f};
  gemm_core(Pb, 2048, ti * 128, Vb, 2048, n0, (ti + 1) * 4, sA, sB, acc);  // causal k-limit
  int lane = threadIdx.x & 63, wave = threadIdx.x >> 6;
  int wm = (wave >> 1) << 6, wn = (wave & 1) << 6;
  int quad = lane >> 4, cl = lane & 15;
  for (int i = 0; i < 4; ++i)
    for (int j = 0; j < 4; ++j)
      for (int rr = 0; rr < 4; ++rr) {
        int row = ti * 128 + wm + i * 16 + quad * 4 + rr;  // t
        int col = n0 + wn + j * 16 + cl;                   // d
        float v = acc[i][j][rr];
        out[((size_t)b * 2048 + row) * 1024 + col] = rintf(v * 10000.f) * 1e-4f;
      }
}

extern "C" void kernel_launch(void* const* d_in, const int* in_sizes, int n_in,
                              void* d_out, int out_size, void* d_ws, size_t ws_size,
                              hipStream_t stream) {
  const float* emb = (const float*)d_in[0];
  const float* Wk = (const float*)d_in[1];
  const float* Wq = (const float*)d_in[2];
  const float* Wv = (const float*)d_in[3];
  float* out = (float*)d_out;

  _Float16* ws = (_Float16*)d_ws;
  _Float16* Xh = ws;                         // 8M halves
  _Float16* Wt = Xh + (size_t)8192 * 1024;   // 3M
  _Float16* Q  = Wt + (size_t)3072 * 1024;   // 8M
  _Float16* K  = Q  + (size_t)8192 * 1024;   // 8M
  _Float16* V  = K  + (size_t)8192 * 1024;   // 8M
  _Float16* Vt = V  + (size_t)8192 * 1024;   // 8M
  _Float16* S  = Vt + (size_t)8192 * 1024;   // 16M  (total 59M halves = 118 MB)

  cast_x_kernel<<<8192, 256, 0, stream>>>(emb, Xh, 2097152);
  wt_kernel<<<dim3(32, 32, 3), 256, 0, stream>>>(Wq, Wk, Wv, Wt);
  qkv_kernel<<<dim3(24, 64), 256, 0, stream>>>(Xh, Wt, Q, K, V);
  vt_kernel<<<dim3(64, 32, 4), 256, 0, stream>>>(V, Vt);
  qk_kernel<<<dim3(136, 4), 256, 0, stream>>>(Q, K, S);
  softmax_kernel<<<8192, 256, 0, stream>>>(S);
  pv_kernel<<<dim3(8, 16, 4), 256, 0, stream>>>(S, Vt, out);
}

// Round 2
// 261.366 us; speedup vs baseline: 1.3481x; 1.3481x over previous
//
#include <hip/hip_runtime.h>
#include <cmath>

typedef _Float16 half8 __attribute__((ext_vector_type(8)));
typedef _Float16 half4 __attribute__((ext_vector_type(4)));
typedef float floatx4 __attribute__((ext_vector_type(4)));

// Direct global->LDS DMA, 16B per lane. LDS dest = uniform base + lane*16.
__device__ __forceinline__ void load_lds16(const void* g, void* l) {
  __builtin_amdgcn_global_load_lds((const __attribute__((address_space(1))) void*)g,
                                   (__attribute__((address_space(3))) void*)l, 16, 0, 0);
}

// ---------------- prep: cast X fp32 -> fp16 ----------------
__global__ void cast_x_kernel(const float* __restrict__ x, _Float16* __restrict__ xh, int n4) {
  int i = blockIdx.x * blockDim.x + threadIdx.x;
  if (i < n4) {
    float4 v = ((const float4*)x)[i];
    half4 h;
    h[0] = (_Float16)v.x; h[1] = (_Float16)v.y; h[2] = (_Float16)v.z; h[3] = (_Float16)v.w;
    ((half4*)xh)[i] = h;
  }
}

// ---------------- prep: W[k][n] fp32 -> Wt[n][k] fp16 (combined Q|K|V) ----------------
__global__ void wt_kernel(const float* __restrict__ Wq, const float* __restrict__ Wk,
                          const float* __restrict__ Wv, _Float16* __restrict__ Wt) {
  __shared__ float tile[32][33];
  int n0 = blockIdx.x * 32, k0 = blockIdx.y * 32, w = blockIdx.z;
  const float* src = (w == 0) ? Wq : (w == 1) ? Wk : Wv;
  int c = threadIdx.x & 31, r8 = threadIdx.x >> 5;
  for (int p = 0; p < 4; ++p) {
    int r = p * 8 + r8;
    tile[r][c] = src[(size_t)(k0 + r) * 1024 + n0 + c];
  }
  __syncthreads();
  for (int p = 0; p < 4; ++p) {
    int rr = p * 8 + r8;  // n within tile
    Wt[(size_t)(w * 1024 + n0 + rr) * 1024 + k0 + c] = (_Float16)tile[c][rr];
  }
}

// ---------------- V[t][d] -> Vt[d][t] fp16 ----------------
__global__ void vt_kernel(const _Float16* __restrict__ V, _Float16* __restrict__ Vt) {
  __shared__ _Float16 tile[32][33];
  int t0 = blockIdx.x * 32, d0 = blockIdx.y * 32, b = blockIdx.z;
  const _Float16* Vb = V + (size_t)b * 2048 * 1024;
  _Float16* Vtb = Vt + (size_t)b * 1024 * 2048;
  int c = threadIdx.x & 31, r8 = threadIdx.x >> 5;
  for (int p = 0; p < 4; ++p) {
    int r = p * 8 + r8;
    tile[r][c] = Vb[(size_t)(t0 + r) * 1024 + d0 + c];
  }
  __syncthreads();
  for (int p = 0; p < 4; ++p) {
    int rr = p * 8 + r8;  // d within tile
    Vtb[(size_t)(d0 + rr) * 2048 + t0 + c] = tile[c][rr];
  }
}

// ---------------- shared GEMM core: C128x128 += A[m][k] * B[n][k]^T ----------------
// A: row-major [M][lda] (k contiguous), B: row-major [N][ldb] (k contiguous).
// 256 threads = 4 waves in 2x2; each wave 64x64 via 4x4 of 16x16x32 MFMA.
// LDS: unpadded 32 halves/row (global_load_lds requires contiguous), bank
// conflicts broken by XOR swizzle: chunk(row,k16) = row*4 + (k16 ^ ((row>>2)&3)).
// Quarter-wave bank-quad = 4*(r&1) + (quad ^ (r>>2)): each of 8 values twice
// -> conflict-free ds_read_b128.
__device__ __forceinline__ void gemm_core(const _Float16* __restrict__ A, int lda, int m0,
                                          const _Float16* __restrict__ B, int ldb, int n0,
                                          int kIters, _Float16* sA, _Float16* sB,
                                          floatx4 acc[4][4]) {
  int tid = threadIdx.x;
  int lane = tid & 63, wave = tid >> 6;
  int wm = (wave >> 1) << 6, wn = (wave & 1) << 6;
  int quad = lane >> 4, r = lane & 15;

  // Staging plan: each buffer = 512 chunks of 16B. Wave w owns chunks
  // [w*128, (w+1)*128) via 2 global_load_lds (64 chunks = 1KB each).
  int c0 = wave * 128 + lane;
  int c1 = c0 + 64;
  int rA0 = c0 >> 2, rA1 = c1 >> 2;
  int k16_0 = (c0 & 3) ^ ((rA0 >> 2) & 3);
  int k16_1 = (c1 & 3) ^ ((rA1 >> 2) & 3);
  const _Float16* gA0 = A + (size_t)(m0 + rA0) * lda + k16_0 * 8;
  const _Float16* gA1 = A + (size_t)(m0 + rA1) * lda + k16_1 * 8;
  const _Float16* gB0 = B + (size_t)(n0 + rA0) * ldb + k16_0 * 8;
  const _Float16* gB1 = B + (size_t)(n0 + rA1) * ldb + k16_1 * 8;
  _Float16* lA0 = sA + wave * 1024;      // 128 chunks * 8 halves
  _Float16* lA1 = lA0 + 512;
  _Float16* lB0 = sB + wave * 1024;
  _Float16* lB1 = lB0 + 512;

  // Fragment LDS offsets (halves), swizzle-consistent with staging.
  int aoff[4], boff[4];
  int sw = quad ^ (r >> 2);
  for (int i = 0; i < 4; ++i) aoff[i] = (((wm + i * 16 + r) << 2) + sw) << 3;
  for (int j = 0; j < 4; ++j) boff[j] = (((wn + j * 16 + r) << 2) + sw) << 3;

  for (int kt = 0; kt < kIters; ++kt) {
    int kb = kt << 5;  // halves
    __syncthreads();
    load_lds16(gA0 + kb, lA0);
    load_lds16(gA1 + kb, lA1);
    load_lds16(gB0 + kb, lB0);
    load_lds16(gB1 + kb, lB1);
    __syncthreads();  // compiler emits s_waitcnt vmcnt(0) before s_barrier
    half8 af[4], bf[4];
    for (int i = 0; i < 4; ++i) af[i] = *(const half8*)(sA + aoff[i]);
    for (int j = 0; j < 4; ++j) bf[j] = *(const half8*)(sB + boff[j]);
    for (int i = 0; i < 4; ++i)
      for (int j = 0; j < 4; ++j)
        acc[i][j] = __builtin_amdgcn_mfma_f32_16x16x32_f16(af[i], bf[j], acc[i][j], 0, 0, 0);
  }
}

// ---------------- QKV projection: [8192x1024] x [3072x1024]^T ----------------
__global__ void qkv_kernel(const _Float16* __restrict__ X, const _Float16* __restrict__ Wt,
                           _Float16* __restrict__ Q, _Float16* __restrict__ K,
                           _Float16* __restrict__ Vv) {
  __shared__ __align__(16) _Float16 sA[4096];
  __shared__ __align__(16) _Float16 sB[4096];
  floatx4 acc[4][4];
  for (int i = 0; i < 4; ++i)
    for (int j = 0; j < 4; ++j) acc[i][j] = (floatx4){0.f, 0.f, 0.f, 0.f};
  int m0 = blockIdx.y * 128, n0 = blockIdx.x * 128;
  gemm_core(X, 1024, m0, Wt, 1024, n0, 32, sA, sB, acc);
  int lane = threadIdx.x & 63, wave = threadIdx.x >> 6;
  int wm = (wave >> 1) << 6, wn = (wave & 1) << 6;
  int quad = lane >> 4, cl = lane & 15;
  int which = n0 >> 10;  // whole block maps to one of Q/K/V (128 | 1024)
  _Float16* dst = (which == 0) ? Q : (which == 1) ? K : Vv;
  int colbase = (n0 & 1023) + wn;
  for (int i = 0; i < 4; ++i)
    for (int j = 0; j < 4; ++j)
      for (int rr = 0; rr < 4; ++rr) {
        int row = m0 + wm + i * 16 + quad * 4 + rr;
        int col = colbase + j * 16 + cl;
        dst[(size_t)row * 1024 + col] = (_Float16)acc[i][j][rr];
      }
}

// ---------------- scores: S[t][s] = Q.K^T / 32, lower-triangular tiles only ----------------
__global__ void qk_kernel(const _Float16* __restrict__ Q, const _Float16* __restrict__ K,
                          _Float16* __restrict__ S) {
  __shared__ __align__(16) _Float16 sA[4096];
  __shared__ __align__(16) _Float16 sB[4096];
  int p = blockIdx.x, b = blockIdx.y;
  int ti = 0;
  while ((ti + 1) * (ti + 2) / 2 <= p) ++ti;
  int tj = p - ti * (ti + 1) / 2;
  const _Float16* Qb = Q + (size_t)b * 2048 * 1024;
  const _Float16* Kb = K + (size_t)b * 2048 * 1024;
  _Float16* Sb = S + (size_t)b * 2048 * 2048;
  floatx4 acc[4][4];
  for (int i = 0; i < 4; ++i)
    for (int j = 0; j < 4; ++j) acc[i][j] = (floatx4){0.f, 0.f, 0.f, 0.f};
  gemm_core(Qb, 1024, ti * 128, Kb, 1024, tj * 128, 32, sA, sB, acc);
  int lane = threadIdx.x & 63, wave = threadIdx.x >> 6;
  int wm = (wave >> 1) << 6, wn = (wave & 1) << 6;
  int quad = lane >> 4, cl = lane & 15;
  for (int i = 0; i < 4; ++i)
    for (int j = 0; j < 4; ++j)
      for (int rr = 0; rr < 4; ++rr) {
        int row = ti * 128 + wm + i * 16 + quad * 4 + rr;
        int col = tj * 128 + wn + j * 16 + cl;
        float val = acc[i][j][rr] * 0.03125f;  // 1/sqrt(1024)
        if (col > row) val = -INFINITY;        // causal mask (diagonal tiles)
        Sb[(size_t)row * 2048 + col] = (_Float16)val;
      }
}

// ---------------- row softmax in place (fp16 S -> fp16 P) ----------------
__global__ void softmax_kernel(_Float16* __restrict__ S) {
  __shared__ float srow[2048];
  __shared__ float redm[4];
  __shared__ float reds[4];
  int idx = blockIdx.x;
  int b = idx >> 11, t = idx & 2047;
  _Float16* row = S + ((size_t)b * 2048 + t) * 2048;
  int rowlen = ((t >> 7) + 1) << 7;  // tile-aligned valid length
  int nch = rowlen >> 3;
  int tid = threadIdx.x;
  int lane = tid & 63, wv = tid >> 6;
  float mx = -INFINITY;
  for (int c = tid; c < nch; c += 256) {
    half8 h = *(const half8*)(row + c * 8);
    for (int e = 0; e < 8; ++e) {
      float f = (float)h[e];
      srow[c * 8 + e] = f;
      mx = fmaxf(mx, f);
    }
  }
  for (int o = 32; o; o >>= 1) mx = fmaxf(mx, __shfl_down(mx, o, 64));
  if (lane == 0) redm[wv] = mx;
  __syncthreads();
  mx = fmaxf(fmaxf(redm[0], redm[1]), fmaxf(redm[2], redm[3]));
  float sum = 0.f;
  for (int c = tid; c < nch; c += 256) {
    for (int e = 0; e < 8; ++e) {
      float ev = __expf(srow[c * 8 + e] - mx);  // exp(-inf)=0 handles mask
      srow[c * 8 + e] = ev;
      sum += ev;
    }
  }
  for (int o = 32; o; o >>= 1) sum += __shfl_down(sum, o, 64);
  if (lane == 0) reds[wv] = sum;
  __syncthreads();
  sum = reds[0] + reds[1] + reds[2] + reds[3];
  float inv = 1.0f / sum;
  for (int c = tid; c < nch; c += 256) {
    half8 h;
    for (int e = 0; e < 8; ++e) h[e] = (_Float16)(srow[c * 8 + e] * inv);
    *(half8*)(row + c * 8) = h;
  }
}

// ---------------- O = P.V : [2048x(kmax)] x [1024x2048]^T, fp32 out ----------------
__global__ void pv_kernel(const _Float16* __restrict__ P, const _Float16* __restrict__ Vt,
                          float* __restrict__ out) {
  __shared__ __align__(16) _Float16 sA[4096];
  __shared__ __align__(16) _Float16 sB[4096];
  int n0 = blockIdx.x * 128, ti = blockIdx.y, b = blockIdx.z;
  const _Float16* Pb = P + (size_t)b * 2048 * 2048;
  const _Float16* Vb = Vt + (size_t)b * 1024 * 2048;
  floatx4 acc[4][4];
  for (int i = 0; i < 4; ++i)
    for (int j = 0; j < 4; ++j) acc[i][j] = (floatx4){0.f, 0.f, 0.f, 0.f};
  gemm_core(Pb, 2048, ti * 128, Vb, 2048, n0, (ti + 1) * 4, sA, sB, acc);  // causal k-limit
  int lane = threadIdx.x & 63, wave = threadIdx.x >> 6;
  int wm = (wave >> 1) << 6, wn = (wave & 1) << 6;
  int quad = lane >> 4, cl = lane & 15;
  for (int i = 0; i < 4; ++i)
    for (int j = 0; j < 4; ++j)
      for (int rr = 0; rr < 4; ++rr) {
        int row = ti * 128 + wm + i * 16 + quad * 4 + rr;  // t
        int col = n0 + wn + j * 16 + cl;                   // d
        float v = acc[i][j][rr];
        out[((size_t)b * 2048 + row) * 1024 + col] = rintf(v * 10000.f) * 1e-4f;
      }
}

extern "C" void kernel_launch(void* const* d_in, const int* in_sizes, int n_in,
                              void* d_out, int out_size, void* d_ws, size_t ws_size,
                              hipStream_t stream) {
  const float* emb = (const float*)d_in[0];
  const float* Wk = (const float*)d_in[1];
  const float* Wq = (const float*)d_in[2];
  const float* Wv = (const float*)d_in[3];
  float* out = (float*)d_out;

  _Float16* ws = (_Float16*)d_ws;
  _Float16* Xh = ws;                         // 8M halves
  _Float16* Wt = Xh + (size_t)8192 * 1024;   // 3M
  _Float16* Q  = Wt + (size_t)3072 * 1024;   // 8M
  _Float16* K  = Q  + (size_t)8192 * 1024;   // 8M
  _Float16* V  = K  + (size_t)8192 * 1024;   // 8M
  _Float16* Vt = V  + (size_t)8192 * 1024;   // 8M
  _Float16* S  = Vt + (size_t)8192 * 1024;   // 16M  (total 59M halves = 118 MB)

  cast_x_kernel<<<8192, 256, 0, stream>>>(emb, Xh, 2097152);
  wt_kernel<<<dim3(32, 32, 3), 256, 0, stream>>>(Wq, Wk, Wv, Wt);
  qkv_kernel<<<dim3(24, 64), 256, 0, stream>>>(Xh, Wt, Q, K, V);
  vt_kernel<<<dim3(64, 32, 4), 256, 0, stream>>>(V, Vt);
  qk_kernel<<<dim3(136, 4), 256, 0, stream>>>(Q, K, S);
  softmax_kernel<<<8192, 256, 0, stream>>>(S);
  pv_kernel<<<dim3(8, 16, 4), 256, 0, stream>>>(S, Vt, out);
}